// Round 5
// baseline (290.051 us; speedup 1.0000x reference)
//
#include <hip/hip_runtime.h>

// MeanAggregator: out[b,:] = mean over DISTINCT nbrs[b,:] of features[idx,:]
// features: [N=200000, D=256] f32 (204.8 MB); nbrs: [B=32768, S=10]; out: [B,256] f32
//
// One wave per output row; lane i owns float4 at columns [4i,4i+4) so each
// feature-row read is one fully-coalesced 1 KB wave access (16 cache lines).
//
// v4 revision: PERSISTENT WAVES + INDEX-PREFETCH PIPELINE.
// Diagnosis from rounds 1/4 (both null): the gather is duty-cycle-bound.
// Old structure = one row per wave = two SERIAL memory epochs per wave
// (index s_load ~900cy with ~0 line pressure, then gathers ~900cy with 160
// lines) -> wave slots hold gather lines in flight only ~50% of the time
// -> measured ~3.1 TB/s = half the streaming read rate. Neither occupancy
// (r4) nor LLC warmth (r1) changes that ratio, hence the nulls.
// Fix: each wave grid-strides over ~4 rows; per iteration it issues row
// r's gathers (vmcnt) and THEN row r+1's index loads (lgkmcnt -- separate
// counter, concurrent), so index latency hides under gather latency and
// line pressure stays up ~90% of wave lifetime.
//  - indices readfirstlane'd -> SGPRs: s_load path, SALU dedupe, saddr
//    gathers sharing one lane*16 voffset VGPR. VGPR ~56 -> 32 waves/CU.
//  - nontemporal store (out is write-only; don't evict feature lines).

#define AGG_S 10
#define AGG_D 256

typedef __attribute__((ext_vector_type(4))) float f32x4;

__global__ __launch_bounds__(256, 8) void MeanAggregator_58514634441194_kernel(
    const float* __restrict__ feat,
    const int* __restrict__ nbrs,
    float* __restrict__ out,
    int B)
{
    const int lane  = threadIdx.x & 63;
    const int wave0 = __builtin_amdgcn_readfirstlane(
        (int)((blockIdx.x * blockDim.x + threadIdx.x) >> 6));
    const int W     = __builtin_amdgcn_readfirstlane(
        (int)((gridDim.x * blockDim.x) >> 6));
    if (wave0 >= B) return;

    // Prologue: indices for this wave's first row (uniform -> s_load).
    int idx[AGG_S];
    {
        const int* __restrict__ row = nbrs + (size_t)wave0 * AGG_S;
#pragma unroll
        for (int s = 0; s < AGG_S; ++s)
            idx[s] = __builtin_amdgcn_readfirstlane(row[s]);
    }

    for (int r = wave0; r < B; r += W) {
        // 1. Issue all 10 gathers for row r back-to-back (160 lines in
        //    flight before the first vmcnt wait). Addresses from SGPR idx.
        float4 v[AGG_S];
#pragma unroll
        for (int s = 0; s < AGG_S; ++s) {
            const float4* __restrict__ p =
                (const float4*)(feat + (size_t)idx[s] * AGG_D);
            v[s] = p[lane];
        }

        // 2. Prefetch NEXT row's indices while the gathers are in flight.
        //    s_load uses lgkmcnt (separate from vmcnt) -> full overlap; the
        //    wait lands just before next iteration's gather issue, ~900cy
        //    after issue here. Clamp instead of branch (always in-bounds).
        const int rn = (r + W < B) ? (r + W) : r;
        int nidx[AGG_S];
        {
            const int* __restrict__ nrow = nbrs + (size_t)rn * AGG_S;
#pragma unroll
            for (int s = 0; s < AGG_S; ++s)
                nidx[s] = __builtin_amdgcn_readfirstlane(nrow[s]);
        }

        // 3. First-occurrence weights from current idx (SALU, overlaps).
        float w[AGG_S];
        float cnt = 0.0f;
#pragma unroll
        for (int s = 0; s < AGG_S; ++s) {
            bool dup = false;
#pragma unroll
            for (int j = 0; j < AGG_S; ++j) {
                if (j < s) dup |= (idx[j] == idx[s]);
            }
            w[s] = dup ? 0.0f : 1.0f;
            cnt += w[s];
        }

        // 4. Consume in issue order (staged vmcnt waits: v[0] ready first).
        float4 acc = make_float4(0.f, 0.f, 0.f, 0.f);
#pragma unroll
        for (int s = 0; s < AGG_S; ++s) {
            acc.x = fmaf(w[s], v[s].x, acc.x);
            acc.y = fmaf(w[s], v[s].y, acc.y);
            acc.z = fmaf(w[s], v[s].z, acc.z);
            acc.w = fmaf(w[s], v[s].w, acc.w);
        }

        const float inv = 1.0f / cnt;
        acc.x *= inv; acc.y *= inv; acc.z *= inv; acc.w *= inv;

        f32x4 accv;
        accv.x = acc.x; accv.y = acc.y; accv.z = acc.z; accv.w = acc.w;
        f32x4* __restrict__ dst = (f32x4*)(out + (size_t)r * AGG_D) + lane;
        __builtin_nontemporal_store(accv, dst);

        // 5. Rotate the pipeline.
#pragma unroll
        for (int s = 0; s < AGG_S; ++s) idx[s] = nidx[s];
    }
}

extern "C" void kernel_launch(void* const* d_in, const int* in_sizes, int n_in,
                              void* d_out, int out_size, void* d_ws, size_t ws_size,
                              hipStream_t stream)
{
    const float* feat = (const float*)d_in[0];
    const int*   nbrs = (const int*)d_in[1];
    float*       out  = (float*)d_out;

    const int B = in_sizes[1] / AGG_S;           // 32768
    const int threads = 256;                     // 4 waves/block
    // Persistent-ish grid: 2048 blocks = 8192 waves = 32 waves/CU at
    // VGPR<=64; each wave grid-strides over ~4 rows so the index-prefetch
    // pipeline stays warm and wave slots never churn.
    int blocks = 2048;
    const int rows_per_block = threads / 64;
    const int max_blocks = (B + rows_per_block - 1) / rows_per_block;
    if (blocks > max_blocks) blocks = max_blocks;

    MeanAggregator_58514634441194_kernel<<<blocks, threads, 0, stream>>>(
        feat, nbrs, out, B);
}